// Round 7
// baseline (254.718 us; speedup 1.0000x reference)
//
#include <hip/hip_runtime.h>
#include <math.h>

#define D 64

typedef __fp16 fp16x2 __attribute__((ext_vector_type(2)));
typedef _Float16 half8 __attribute__((ext_vector_type(8)));
typedef _Float16 half4v __attribute__((ext_vector_type(4)));
typedef __attribute__((ext_vector_type(4))) float f32x4;

union h8pun { half8 v; fp16x2 h2[4]; };

// ---------------------------------------------------------------------------
// Prep: weight transposes + segment boundaries in one kernel.
__global__ __launch_bounds__(256) void k_prep(const float* __restrict__ W1,
                                              const float* __restrict__ W2,
                                              float* __restrict__ W1at,
                                              float* __restrict__ W1bt,
                                              float* __restrict__ W2t,
                                              const int* __restrict__ seg_ids,
                                              int* __restrict__ start, int E, int N) {
    int i = blockIdx.x * 256 + threadIdx.x;
    if (i < 3 * D * D) {
        int mat = i / (D * D), j = i % (D * D);
        int r = j >> 6, c = j & 63;
        if (mat == 0)      W1at[c * D + r] = W1[r * D + c];
        else if (mat == 1) W1bt[c * D + r] = W1[(D + r) * D + c];
        else               W2t[c * D + r] = W2[r * D + c];
    }
    if (i <= N) {
        int lo = 0, hi = E;
        while (lo < hi) {
            int mid = (lo + hi) >> 1;
            if (seg_ids[mid] < i) lo = mid + 1; else hi = mid;
        }
        start[i] = lo;
    }
}

// ---------------------------------------------------------------------------
// Combined MFMA row-projection (fp16).
// Waves [0, wavesU):   ue[u] = [u2e_h(64) | q(64)]  (interleaved, stride 128)
// Waves [wavesU, ..):  p[r] = u2e[nodes[r]] @ W1b + b1   (stride 64)
__global__ __launch_bounds__(256) void k_proj_both(const float* __restrict__ u2e,
                                                   const int* __restrict__ nodes,
                                                   const float* __restrict__ W1at,
                                                   const float* __restrict__ W1bt,
                                                   const float* __restrict__ b1,
                                                   _Float16* __restrict__ ue,
                                                   _Float16* __restrict__ p,
                                                   int U, int N, int wavesU, int wavesN) {
    int lane = threadIdx.x & 63;
    int m = lane & 15, quad = lane >> 4;
    int wave = (blockIdx.x * blockDim.x + threadIdx.x) >> 6;

    const float* Wt;
    const int* idx;
    const float* bias;
    _Float16* outp;
    _Float16* copyp;
    int R, w0, wstride, ostride;
    if (wave < wavesU) {
        Wt = W1at; idx = nullptr; bias = nullptr;
        outp = ue + D; copyp = ue; ostride = 2 * D;
        R = U; w0 = wave; wstride = wavesU;
    } else {
        Wt = W1bt; idx = nodes; bias = b1;
        outp = p; copyp = nullptr; ostride = D;
        R = N; w0 = wave - wavesU; wstride = wavesN;
    }

    half8 Bf[2][4];
    float bv[4];
#pragma unroll
    for (int t = 0; t < 4; ++t) {
        int n = m + 16 * t;
        bv[t] = bias ? bias[n] : 0.0f;
#pragma unroll
        for (int kh = 0; kh < 2; ++kh) {
            const float* col = Wt + n * D + kh * 32 + quad * 8;
#pragma unroll
            for (int j = 0; j < 8; ++j) Bf[kh][t][j] = (_Float16)col[j];
        }
    }

    int ngroups = (R + 15) / 16;
    for (int g = w0; g < ngroups; g += wstride) {
        int r_ = g * 16 + m;
        int rs = r_ < R ? r_ : R - 1;
        int src = idx ? idx[rs] : rs;
        const float4* arow = (const float4*)(u2e + (size_t)src * D);
        float4 x0 = arow[quad * 2], x1 = arow[quad * 2 + 1];
        float4 y0 = arow[8 + quad * 2], y1 = arow[8 + quad * 2 + 1];
        h8pun A0, A1;
        A0.h2[0] = __builtin_amdgcn_cvt_pkrtz(x0.x, x0.y);
        A0.h2[1] = __builtin_amdgcn_cvt_pkrtz(x0.z, x0.w);
        A0.h2[2] = __builtin_amdgcn_cvt_pkrtz(x1.x, x1.y);
        A0.h2[3] = __builtin_amdgcn_cvt_pkrtz(x1.z, x1.w);
        A1.h2[0] = __builtin_amdgcn_cvt_pkrtz(y0.x, y0.y);
        A1.h2[1] = __builtin_amdgcn_cvt_pkrtz(y0.z, y0.w);
        A1.h2[2] = __builtin_amdgcn_cvt_pkrtz(y1.x, y1.y);
        A1.h2[3] = __builtin_amdgcn_cvt_pkrtz(y1.z, y1.w);
        if (copyp && r_ < R) {
            *(half8*)(copyp + (size_t)r_ * 2 * D + quad * 8) = A0.v;
            *(half8*)(copyp + (size_t)r_ * 2 * D + 32 + quad * 8) = A1.v;
        }
        f32x4 C[4];
#pragma unroll
        for (int t = 0; t < 4; ++t) C[t] = (f32x4){bv[t], bv[t], bv[t], bv[t]};
#pragma unroll
        for (int t = 0; t < 4; ++t) {
            C[t] = __builtin_amdgcn_mfma_f32_16x16x32_f16(A0.v, Bf[0][t], C[t], 0, 0, 0);
            C[t] = __builtin_amdgcn_mfma_f32_16x16x32_f16(A1.v, Bf[1][t], C[t], 0, 0, 0);
        }
#pragma unroll
        for (int r = 0; r < 4; ++r) {
            int row = g * 16 + quad * 4 + r;
            if (row < R) {
#pragma unroll
                for (int t = 0; t < 4; ++t)
                    outp[(size_t)row * ostride + m + 16 * t] = (_Float16)C[t][r];
            }
        }
    }
}

// ---------------------------------------------------------------------------
// Fused edge-MLP + online segment softmax + aggregation.  One wave per segment
// (grid-stride).  Per 16-edge chunk: gather q rows, MFMA layer2, logits via
// butterfly reduce, online (max, sum-exp) update, weighted aggregation of the
// u2e_h halves of the same interleaved rows (cache-hot from the q gather).
__global__ __launch_bounds__(256) void k_fused(const int* __restrict__ nodes,
                                               const int* __restrict__ neigh_idx,
                                               const float* __restrict__ u2e,
                                               const _Float16* __restrict__ ue,
                                               const _Float16* __restrict__ p,
                                               const float* __restrict__ W2t,
                                               const float* __restrict__ b2,
                                               const float* __restrict__ w3,
                                               const int* __restrict__ start,
                                               float* __restrict__ out, int N) {
    int lane = threadIdx.x & 63;
    int m = lane & 15, quad = lane >> 4;

    half8 Bf[2][4];
    float b2v[4], w3v[4];
#pragma unroll
    for (int t = 0; t < 4; ++t) {
        int nn = m + 16 * t;
        b2v[t] = b2[nn];
        w3v[t] = w3[nn];
#pragma unroll
        for (int kh = 0; kh < 2; ++kh) {
            const float* col = W2t + nn * D + kh * 32 + quad * 8;
#pragma unroll
            for (int j = 0; j < 8; ++j) Bf[kh][t][j] = (_Float16)col[j];
        }
    }
    const half8 hz = {0, 0, 0, 0, 0, 0, 0, 0};

    int wave = (blockIdx.x * blockDim.x + threadIdx.x) >> 6;
    int nwaves = (gridDim.x * blockDim.x) >> 6;
    for (int n = wave; n < N; n += nwaves) {
        int s = start[n];
        int t = start[n + 1];
        if (s == t) {  // no neighbors: own embedding (fp32, exact)
            int node = nodes[n];
            out[(size_t)n * D + lane] = u2e[(size_t)node * D + lane];
            continue;
        }
        const half8* prow = (const half8*)(p + (size_t)n * D);
        half8 pa0 = prow[quad], pa1 = prow[quad + 4];
        float m_run = -1e30f, ssum = 0.0f;
        float acc0 = 0.f, acc1 = 0.f, acc2 = 0.f, acc3 = 0.f;
        for (int base = s; base < t; base += 16) {
            int e = base + m;
            int es = e < t ? e : t - 1;
            int nb = neigh_idx[es];
            const half8* qrow = (const half8*)(ue + (size_t)nb * (2 * D) + D);
            half8 qa0 = qrow[quad], qa1 = qrow[quad + 4];
            half8 A0 = __builtin_elementwise_max(qa0 + pa0, hz);
            half8 A1 = __builtin_elementwise_max(qa1 + pa1, hz);
            f32x4 C[4];
#pragma unroll
            for (int t4 = 0; t4 < 4; ++t4) C[t4] = (f32x4){b2v[t4], b2v[t4], b2v[t4], b2v[t4]};
#pragma unroll
            for (int t4 = 0; t4 < 4; ++t4) {
                C[t4] = __builtin_amdgcn_mfma_f32_16x16x32_f16(A0, Bf[0][t4], C[t4], 0, 0, 0);
                C[t4] = __builtin_amdgcn_mfma_f32_16x16x32_f16(A1, Bf[1][t4], C[t4], 0, 0, 0);
            }
            float lw[4];
#pragma unroll
            for (int r = 0; r < 4; ++r) {
                float sa = 0.0f;
#pragma unroll
                for (int t4 = 0; t4 < 4; ++t4)
                    sa += fmaxf(C[t4][r], 0.0f) * w3v[t4];
                lw[r] = sa;
            }
#pragma unroll
            for (int off = 1; off <= 8; off <<= 1) {
#pragma unroll
                for (int r = 0; r < 4; ++r) lw[r] += __shfl_xor(lw[r], off, 64);
            }
            // mask invalid edges of the tail chunk
#pragma unroll
            for (int r = 0; r < 4; ++r)
                if (base + quad * 4 + r >= t) lw[r] = -1e30f;
            // online softmax update
            float mc = fmaxf(fmaxf(lw[0], lw[1]), fmaxf(lw[2], lw[3]));
            mc = fmaxf(mc, __shfl_xor(mc, 16, 64));
            mc = fmaxf(mc, __shfl_xor(mc, 32, 64));
            float mnew = fmaxf(m_run, mc);
            float scale = __expf(m_run - mnew);
            float w[4];
            float wsum = 0.0f;
#pragma unroll
            for (int r = 0; r < 4; ++r) { w[r] = __expf(lw[r] - mnew); wsum += w[r]; }
            wsum += __shfl_xor(wsum, 16, 64);
            wsum += __shfl_xor(wsum, 32, 64);
            ssum = ssum * scale + wsum;
            acc0 *= scale; acc1 *= scale; acc2 *= scale; acc3 *= scale;
            // aggregation: quad handles its own 4 edges; lane m covers cols 4m..4m+3
#pragma unroll
            for (int r = 0; r < 4; ++r) {
                int nbr = __shfl(nb, 4 * quad + r, 64);
                half4v row = *(const half4v*)(ue + (size_t)nbr * (2 * D) + m * 4);
                acc0 += w[r] * (float)row[0];
                acc1 += w[r] * (float)row[1];
                acc2 += w[r] * (float)row[2];
                acc3 += w[r] * (float)row[3];
            }
            m_run = mnew;
        }
        // reduce partial sums across the 4 quads
#pragma unroll
        for (int off = 16; off <= 32; off <<= 1) {
            acc0 += __shfl_xor(acc0, off, 64);
            acc1 += __shfl_xor(acc1, off, 64);
            acc2 += __shfl_xor(acc2, off, 64);
            acc3 += __shfl_xor(acc3, off, 64);
        }
        float inv = 1.0f / ssum;
        if (quad == 0)
            *(float4*)(out + (size_t)n * D + m * 4) =
                make_float4(acc0 * inv, acc1 * inv, acc2 * inv, acc3 * inv);
    }
}

// ---------------------------------------------------------------------------
extern "C" void kernel_launch(void* const* d_in, const int* in_sizes, int n_in,
                              void* d_out, int out_size, void* d_ws, size_t ws_size,
                              hipStream_t stream) {
    const int* nodes = (const int*)d_in[0];
    const int* neigh_idx = (const int*)d_in[1];
    const int* seg_ids = (const int*)d_in[2];
    const float* u2e = (const float*)d_in[3];
    const float* W1 = (const float*)d_in[4];
    const float* b1 = (const float*)d_in[5];
    const float* W2 = (const float*)d_in[6];
    const float* b2 = (const float*)d_in[7];
    const float* w3 = (const float*)d_in[8];
    const float* b3 = (const float*)d_in[9];
    (void)b3;  // softmax shift-invariant — b3 cancels
    float* out = (float*)d_out;

    int N = in_sizes[0];
    int E = in_sizes[1];
    int U = in_sizes[3] / D;

    char* ws = (char*)d_ws;
    size_t off = 0;
    auto alloc = [&](size_t bytes) {
        void* ptr = ws + off;
        off = (off + bytes + 255) & ~(size_t)255;
        return ptr;
    };
    int* start = (int*)alloc((size_t)(N + 1) * 4);
    float* W1at = (float*)alloc((size_t)D * D * 4);
    float* W1bt = (float*)alloc((size_t)D * D * 4);
    float* W2t = (float*)alloc((size_t)D * D * 4);
    _Float16* ue = (_Float16*)alloc((size_t)U * 2 * D * 2);  // [u2e_h | q] interleaved
    _Float16* p = (_Float16*)alloc((size_t)N * D * 2);
    (void)ws_size;

    int prep_n = (N + 1) > 3 * D * D ? (N + 1) : 3 * D * D;
    k_prep<<<(prep_n + 255) / 256, 256, 0, stream>>>(W1, W2, W1at, W1bt, W2t,
                                                     seg_ids, start, E, N);
    const int wavesU = 4096, wavesN = 1024;
    k_proj_both<<<(wavesU + wavesN) / 4, 256, 0, stream>>>(u2e, nodes, W1at, W1bt, b1,
                                                           ue, p, U, N, wavesU, wavesN);
    k_fused<<<4096, 256, 0, stream>>>(nodes, neigh_idx, u2e, ue, p, W2t, b2, w3,
                                      start, out, N);
}

// Round 8
// 238.482 us; speedup vs baseline: 1.0681x; 1.0681x over previous
//
#include <hip/hip_runtime.h>
#include <math.h>

#define D 64

typedef __fp16 fp16x2 __attribute__((ext_vector_type(2)));
typedef _Float16 half8 __attribute__((ext_vector_type(8)));
typedef _Float16 half4v __attribute__((ext_vector_type(4)));
typedef __attribute__((ext_vector_type(4))) float f32x4;

union h8pun { half8 v; fp16x2 h2[4]; };

// ---------------------------------------------------------------------------
// Prep: W1at/W1bt transposes, permuted W2pt, segment boundaries.
// W2pt[n][pos] = W2[pi_inv(pos)][n],  pi_inv(pos) = (pos>>2) + 16*(pos&3).
// (q/p are stored with cols permuted by pi(col m+16t)=m*4+t; W2pt compensates.)
__global__ __launch_bounds__(256) void k_prep(const float* __restrict__ W1,
                                              const float* __restrict__ W2,
                                              float* __restrict__ W1at,
                                              float* __restrict__ W1bt,
                                              float* __restrict__ W2pt,
                                              const int* __restrict__ seg_ids,
                                              int* __restrict__ start, int E, int N) {
    int i = blockIdx.x * 256 + threadIdx.x;
    if (i < 3 * D * D) {
        int mat = i / (D * D), j = i % (D * D);
        if (mat == 0) {
            int r = j >> 6, c = j & 63;
            W1at[c * D + r] = W1[r * D + c];
        } else if (mat == 1) {
            int r = j >> 6, c = j & 63;
            W1bt[c * D + r] = W1[(D + r) * D + c];
        } else {
            int n = j >> 6, pos = j & 63;
            int k = (pos >> 2) + 16 * (pos & 3);   // pi_inv
            W2pt[n * D + pos] = W2[k * D + n];
        }
    }
    if (i <= N) {
        int lo = 0, hi = E;
        while (lo < hi) {
            int mid = (lo + hi) >> 1;
            if (seg_ids[mid] < i) lo = mid + 1; else hi = mid;
        }
        start[i] = lo;
    }
}

// ---------------------------------------------------------------------------
// Combined MFMA row-projection (fp16), both passes in one launch.
// Waves [0, wavesU):     q~[r] = pi(u2e[r] @ W1a), u2e_h[r] = fp16(u2e[r])
// Waves [wavesU, ...):   p~[r] = pi(u2e[nodes[r]] @ W1b + b1)
// pi-layout store: lane writes one contiguous half4 per row (coalesced 128 B).
__global__ __launch_bounds__(256) void k_proj_both(const float* __restrict__ u2e,
                                                   const int* __restrict__ nodes,
                                                   const float* __restrict__ W1at,
                                                   const float* __restrict__ W1bt,
                                                   const float* __restrict__ b1,
                                                   _Float16* __restrict__ q,
                                                   _Float16* __restrict__ u2e_h,
                                                   _Float16* __restrict__ p,
                                                   int U, int N, int wavesU, int wavesN) {
    int lane = threadIdx.x & 63;
    int m = lane & 15, quad = lane >> 4;
    int wave = (blockIdx.x * blockDim.x + threadIdx.x) >> 6;

    const float* Wt;
    const int* idx;
    const float* bias;
    _Float16* outp;
    _Float16* copyp;
    int R, w0, wstride;
    if (wave < wavesU) {
        Wt = W1at; idx = nullptr; bias = nullptr; outp = q; copyp = u2e_h;
        R = U; w0 = wave; wstride = wavesU;
    } else {
        Wt = W1bt; idx = nodes; bias = b1; outp = p; copyp = nullptr;
        R = N; w0 = wave - wavesU; wstride = wavesN;
    }

    half8 Bf[2][4];
    float bv[4];
#pragma unroll
    for (int t = 0; t < 4; ++t) {
        int n = m + 16 * t;
        bv[t] = bias ? bias[n] : 0.0f;
#pragma unroll
        for (int kh = 0; kh < 2; ++kh) {
            const float* col = Wt + n * D + kh * 32 + quad * 8;
#pragma unroll
            for (int j = 0; j < 8; ++j) Bf[kh][t][j] = (_Float16)col[j];
        }
    }

    int ngroups = (R + 15) / 16;
    for (int g = w0; g < ngroups; g += wstride) {
        int r_ = g * 16 + m;
        int rs = r_ < R ? r_ : R - 1;
        int src = idx ? idx[rs] : rs;
        const float4* arow = (const float4*)(u2e + (size_t)src * D);
        float4 x0 = arow[quad * 2], x1 = arow[quad * 2 + 1];
        float4 y0 = arow[8 + quad * 2], y1 = arow[8 + quad * 2 + 1];
        h8pun A0, A1;
        A0.h2[0] = __builtin_amdgcn_cvt_pkrtz(x0.x, x0.y);
        A0.h2[1] = __builtin_amdgcn_cvt_pkrtz(x0.z, x0.w);
        A0.h2[2] = __builtin_amdgcn_cvt_pkrtz(x1.x, x1.y);
        A0.h2[3] = __builtin_amdgcn_cvt_pkrtz(x1.z, x1.w);
        A1.h2[0] = __builtin_amdgcn_cvt_pkrtz(y0.x, y0.y);
        A1.h2[1] = __builtin_amdgcn_cvt_pkrtz(y0.z, y0.w);
        A1.h2[2] = __builtin_amdgcn_cvt_pkrtz(y1.x, y1.y);
        A1.h2[3] = __builtin_amdgcn_cvt_pkrtz(y1.z, y1.w);
        if (copyp && r_ < R) {
            *(half8*)(copyp + (size_t)r_ * D + quad * 8) = A0.v;
            *(half8*)(copyp + (size_t)r_ * D + 32 + quad * 8) = A1.v;
        }
        f32x4 C[4];
#pragma unroll
        for (int t = 0; t < 4; ++t) C[t] = (f32x4){bv[t], bv[t], bv[t], bv[t]};
#pragma unroll
        for (int t = 0; t < 4; ++t) {
            C[t] = __builtin_amdgcn_mfma_f32_16x16x32_f16(A0.v, Bf[0][t], C[t], 0, 0, 0);
            C[t] = __builtin_amdgcn_mfma_f32_16x16x32_f16(A1.v, Bf[1][t], C[t], 0, 0, 0);
        }
        // pi-layout store: position m*4+t holds col m+16t -> one half4 per row.
#pragma unroll
        for (int r = 0; r < 4; ++r) {
            int row = g * 16 + quad * 4 + r;
            if (row < R) {
                half4v hv = {(_Float16)C[0][r], (_Float16)C[1][r],
                             (_Float16)C[2][r], (_Float16)C[3][r]};
                *(half4v*)(outp + (size_t)row * D + m * 4) = hv;
            }
        }
    }
}

// ---------------------------------------------------------------------------
// Edge logits via fp16 MFMA, 32 edges per wave-iteration (two A-sets share
// B-frags).  q/p are in pi-layout; W2pt is permuted to match.
__global__ __launch_bounds__(256) void k_edge_logits_mfma(const int* __restrict__ neigh_idx,
                                                          const int* __restrict__ seg_ids,
                                                          const _Float16* __restrict__ q,
                                                          const _Float16* __restrict__ p,
                                                          const float* __restrict__ W2pt,
                                                          const float* __restrict__ b2,
                                                          const float* __restrict__ w3,
                                                          const float* __restrict__ b3,
                                                          float* __restrict__ logits, int E) {
    int lane = threadIdx.x & 63;
    int m = lane & 15, quad = lane >> 4;

    half8 Bf[2][4];
    float b2v[4], w3v[4];
#pragma unroll
    for (int t = 0; t < 4; ++t) {
        int n = m + 16 * t;
        b2v[t] = b2[n];
        w3v[t] = w3[n];
#pragma unroll
        for (int kh = 0; kh < 2; ++kh) {
            const float* col = W2pt + n * D + kh * 32 + quad * 8;
#pragma unroll
            for (int j = 0; j < 8; ++j) Bf[kh][t][j] = (_Float16)col[j];
        }
    }
    float b3v = b3[0];
    const half8 hz = {0, 0, 0, 0, 0, 0, 0, 0};

    int ngroups = (E + 31) / 32;
    int wave = (blockIdx.x * blockDim.x + threadIdx.x) >> 6;
    int nwaves = (gridDim.x * blockDim.x) >> 6;
    for (int g = wave; g < ngroups; g += nwaves) {
        int ea = g * 32 + m, eb = ea + 16;
        int eas = ea < E ? ea : E - 1;
        int ebs = eb < E ? eb : E - 1;
        int nbra = neigh_idx[eas], sega = seg_ids[eas];
        int nbrb = neigh_idx[ebs], segb = seg_ids[ebs];
        const half8* qra = (const half8*)(q + (size_t)nbra * D);
        const half8* pra = (const half8*)(p + (size_t)sega * D);
        const half8* qrb = (const half8*)(q + (size_t)nbrb * D);
        const half8* prb = (const half8*)(p + (size_t)segb * D);
        half8 qa0 = qra[quad], qa1 = qra[quad + 4];
        half8 pa0 = pra[quad], pa1 = pra[quad + 4];
        half8 qb0 = qrb[quad], qb1 = qrb[quad + 4];
        half8 pb0 = prb[quad], pb1 = prb[quad + 4];
        half8 Aa0 = __builtin_elementwise_max(qa0 + pa0, hz);
        half8 Aa1 = __builtin_elementwise_max(qa1 + pa1, hz);
        half8 Ab0 = __builtin_elementwise_max(qb0 + pb0, hz);
        half8 Ab1 = __builtin_elementwise_max(qb1 + pb1, hz);
        f32x4 Ca[4], Cb[4];
#pragma unroll
        for (int t = 0; t < 4; ++t) {
            Ca[t] = (f32x4){b2v[t], b2v[t], b2v[t], b2v[t]};
            Cb[t] = Ca[t];
        }
#pragma unroll
        for (int t = 0; t < 4; ++t) {
            Ca[t] = __builtin_amdgcn_mfma_f32_16x16x32_f16(Aa0, Bf[0][t], Ca[t], 0, 0, 0);
            Ca[t] = __builtin_amdgcn_mfma_f32_16x16x32_f16(Aa1, Bf[1][t], Ca[t], 0, 0, 0);
            Cb[t] = __builtin_amdgcn_mfma_f32_16x16x32_f16(Ab0, Bf[0][t], Cb[t], 0, 0, 0);
            Cb[t] = __builtin_amdgcn_mfma_f32_16x16x32_f16(Ab1, Bf[1][t], Cb[t], 0, 0, 0);
        }
        float pa[4], pb[4];
#pragma unroll
        for (int r = 0; r < 4; ++r) {
            float sa = 0.0f, sb = 0.0f;
#pragma unroll
            for (int t = 0; t < 4; ++t) {
                sa += fmaxf(Ca[t][r], 0.0f) * w3v[t];
                sb += fmaxf(Cb[t][r], 0.0f) * w3v[t];
            }
            pa[r] = sa; pb[r] = sb;
        }
#pragma unroll
        for (int off = 1; off <= 8; off <<= 1) {
#pragma unroll
            for (int r = 0; r < 4; ++r) {
                pa[r] += __shfl_xor(pa[r], off, 64);
                pb[r] += __shfl_xor(pb[r], off, 64);
            }
        }
        if (m == 0) {
            int e0 = g * 32 + quad * 4;
            if (e0 + 3 < E)
                *(float4*)(logits + e0) = make_float4(pa[0] + b3v, pa[1] + b3v, pa[2] + b3v, pa[3] + b3v);
            else
#pragma unroll
                for (int r = 0; r < 4; ++r)
                    if (e0 + r < E) logits[e0 + r] = pa[r] + b3v;
            int e1 = e0 + 16;
            if (e1 + 3 < E)
                *(float4*)(logits + e1) = make_float4(pb[0] + b3v, pb[1] + b3v, pb[2] + b3v, pb[3] + b3v);
            else
#pragma unroll
                for (int r = 0; r < 4; ++r)
                    if (e1 + r < E) logits[e1 + r] = pb[r] + b3v;
        }
    }
}

// ---------------------------------------------------------------------------
// Wave per node: softmax stats, then aggregation from fp16 u2e copy.
// 8 lane-groups x 4-deep unroll = 32 neighbor rows in flight per wave.
__global__ __launch_bounds__(256) void k_agg(const int* __restrict__ nodes,
                                             const int* __restrict__ neigh_idx,
                                             const float* __restrict__ u2e,
                                             const _Float16* __restrict__ u2e_h,
                                             const float* __restrict__ logits,
                                             const int* __restrict__ start,
                                             float* __restrict__ out, int N) {
    int n = blockIdx.x * 4 + ((int)threadIdx.x >> 6);
    int lane = threadIdx.x & 63;
    if (n >= N) return;
    int s = start[n];
    int t = start[n + 1];
    if (s == t) {  // no neighbors: own embedding (fp32, exact)
        int node = nodes[n];
        out[(size_t)n * D + lane] = u2e[(size_t)node * D + lane];
        return;
    }
    float mx = -INFINITY;
    for (int i = s + lane; i < t; i += 64) mx = fmaxf(mx, logits[i]);
#pragma unroll
    for (int off = 32; off >= 1; off >>= 1) mx = fmaxf(mx, __shfl_xor(mx, off, 64));
    float ssum = 0.0f;
    for (int i = s + lane; i < t; i += 64) ssum += __expf(logits[i] - mx);
#pragma unroll
    for (int off = 32; off >= 1; off >>= 1) ssum += __shfl_xor(ssum, off, 64);
    float inv = 1.0f / ssum;

    int grp = lane >> 3, sub = lane & 7;   // 8 groups of 8 lanes
    float acc[8];
#pragma unroll
    for (int j = 0; j < 8; ++j) acc[j] = 0.0f;
    for (int i = s; i < t; i += 32) {
#pragma unroll
        for (int uu = 0; uu < 4; ++uu) {
            int ii = i + uu * 8 + grp;
            bool v = ii < t;
            int is = v ? ii : s;
            float lg = logits[is];
            int nb = neigh_idx[is];
            half8 r = *(const half8*)(u2e_h + (size_t)nb * D + sub * 8);
            float a = v ? __expf(lg - mx) * inv : 0.0f;
#pragma unroll
            for (int j = 0; j < 8; ++j) acc[j] += a * (float)r[j];
        }
    }
#pragma unroll
    for (int off = 8; off <= 32; off <<= 1) {
#pragma unroll
        for (int j = 0; j < 8; ++j) acc[j] += __shfl_xor(acc[j], off, 64);
    }
    if (grp == 0) {
        float* o = out + (size_t)n * D + sub * 8;
        *(float4*)o = make_float4(acc[0], acc[1], acc[2], acc[3]);
        *(float4*)(o + 4) = make_float4(acc[4], acc[5], acc[6], acc[7]);
    }
}

// ---------------------------------------------------------------------------
extern "C" void kernel_launch(void* const* d_in, const int* in_sizes, int n_in,
                              void* d_out, int out_size, void* d_ws, size_t ws_size,
                              hipStream_t stream) {
    const int* nodes = (const int*)d_in[0];
    const int* neigh_idx = (const int*)d_in[1];
    const int* seg_ids = (const int*)d_in[2];
    const float* u2e = (const float*)d_in[3];
    const float* W1 = (const float*)d_in[4];
    const float* b1 = (const float*)d_in[5];
    const float* W2 = (const float*)d_in[6];
    const float* b2 = (const float*)d_in[7];
    const float* w3 = (const float*)d_in[8];
    const float* b3 = (const float*)d_in[9];
    float* out = (float*)d_out;

    int N = in_sizes[0];
    int E = in_sizes[1];
    int U = in_sizes[3] / D;

    char* ws = (char*)d_ws;
    size_t off = 0;
    auto alloc = [&](size_t bytes) {
        void* ptr = ws + off;
        off = (off + bytes + 255) & ~(size_t)255;
        return ptr;
    };
    float* logits = (float*)alloc((size_t)E * 4);
    int* start = (int*)alloc((size_t)(N + 1) * 4);
    float* W1at = (float*)alloc((size_t)D * D * 4);
    float* W1bt = (float*)alloc((size_t)D * D * 4);
    float* W2pt = (float*)alloc((size_t)D * D * 4);
    _Float16* q = (_Float16*)alloc((size_t)U * D * 2);
    _Float16* p = (_Float16*)alloc((size_t)N * D * 2);
    _Float16* u2e_h = (_Float16*)alloc((size_t)U * D * 2);
    (void)ws_size;

    int prep_n = (N + 1) > 3 * D * D ? (N + 1) : 3 * D * D;
    k_prep<<<(prep_n + 255) / 256, 256, 0, stream>>>(W1, W2, W1at, W1bt, W2pt,
                                                     seg_ids, start, E, N);
    const int wavesU = 4096, wavesN = 1024;
    k_proj_both<<<(wavesU + wavesN) / 4, 256, 0, stream>>>(u2e, nodes, W1at, W1bt, b1,
                                                           q, u2e_h, p, U, N, wavesU, wavesN);
    k_edge_logits_mfma<<<2048, 256, 0, stream>>>(neigh_idx, seg_ids, q, p, W2pt,
                                                 b2, w3, b3, logits, E);
    k_agg<<<(N + 3) / 4, 256, 0, stream>>>(nodes, neigh_idx, u2e, u2e_h, logits, start, out, N);
}